// Round 13
// baseline (254.157 us; speedup 1.0000x reference)
//
#include <hip/hip_runtime.h>

#define NB 4
#define CHN 512
#define HWD 4096
#define LTOT (NB*HWD)
#define FEAT_ 256
#define POOL_ 8192

typedef __attribute__((ext_vector_type(8))) __bf16 bf16x8;
typedef __attribute__((ext_vector_type(8))) unsigned short u16x8;
typedef __attribute__((ext_vector_type(8))) _Float16 f16x8;
typedef __attribute__((ext_vector_type(4))) unsigned u32x4;
typedef __attribute__((ext_vector_type(4))) float f32x4;
typedef __attribute__((ext_vector_type(16))) float f32x16;

static __device__ __forceinline__ float fexp2(float x){
  return __builtin_amdgcn_exp2f(x);   // raw v_exp_f32 (2^x)
}

static __device__ __forceinline__ unsigned short f2bf(float f){
  union { float f; unsigned u; } c; c.f = f;
  unsigned u = c.u;
  u += 0x7fffu + ((u >> 16) & 1u);   // round-to-nearest-even
  return (unsigned short)(u >> 16);
}

static __device__ __forceinline__ unsigned pk_f16(float lo, float hi){
  auto r = __builtin_amdgcn_cvt_pkrtz(lo, hi);   // __fp16 ext_vector(2)
  return __builtin_bit_cast(unsigned, r);        // [15:0]=f16(lo), [31:16]=f16(hi)
}

static __device__ __forceinline__ f32x4 mfma16(bf16x8 a, bf16x8 b, f32x4 c){
  return __builtin_amdgcn_mfma_f32_16x16x32_bf16(a, b, c, 0, 0, 0);
}
static __device__ __forceinline__ f32x16 mfma32b(bf16x8 a, bf16x8 b, f32x16 c){
  return __builtin_amdgcn_mfma_f32_32x32x16_bf16(a, b, c, 0, 0, 0);
}
static __device__ __forceinline__ f32x16 mfma32h(f16x8 a, f16x8 b, f32x16 c){
  return __builtin_amdgcn_mfma_f32_32x32x16_f16(a, b, c, 0, 0, 0);
}

static __device__ __forceinline__ bf16x8 ld_bf8(const void* p){
  u16x8 v = *(const u16x8*)p;
  return __builtin_bit_cast(bf16x8, v);
}
static __device__ __forceinline__ f16x8 ld_f8(const void* p){
  u16x8 v = *(const u16x8*)p;
  return __builtin_bit_cast(f16x8, v);
}

static __device__ __forceinline__ void gload16(const void* g, void* l){
  __builtin_amdgcn_global_load_lds((const __attribute__((address_space(1))) void*)g,
                                   (__attribute__((address_space(3))) void*)l, 16, 0, 0);
}

// ---------------- f32 -> bf16 convert (layout-preserving) ----------------
__global__ void k_cvt(const float* __restrict__ src, unsigned short* __restrict__ dst, int n4){
  int i = blockIdx.x * 256 + threadIdx.x;
  if (i < n4) {
    const float4 v = *(const float4*)(src + (size_t)i * 4);
    ushort4 o; o.x = f2bf(v.x); o.y = f2bf(v.y); o.z = f2bf(v.z); o.w = f2bf(v.w);
    *(ushort4*)(dst + (size_t)i * 4) = o;
  }
}

// ---------------- pool -> poolKF: A-fragment-major K (bf16, swapped QK^T) ----
// poolKF[t][kc][lane][8]: lane's 16B = K[p = t*32 + (lane&31)]
//                                       [f = kc*16 + (lane>>5)*8 + j]
__global__ __launch_bounds__(256) void k_poolKF(const float* __restrict__ pool,
                                                unsigned short* __restrict__ poolKF){
  int t = blockIdx.x >> 2;
  int tid = threadIdx.x;
  int kc = ((blockIdx.x & 3) << 2) | (tid >> 6);
  int lane = tid & 63;
  int p = t*32 + (lane & 31);
  int f0 = kc*16 + (lane >> 5)*8;
  u16x8 o;
  #pragma unroll
  for (int j = 0; j < 8; ++j) o[j] = f2bf(pool[(size_t)(f0+j)*POOL_ + p]);
  *(u16x8*)((char*)poolKF + (size_t)t*16384 + kc*1024 + lane*16) = o;
}

// ---------------- pool -> poolVF: B-fragment-major V (f16, reg-order sigma) --
// poolVF[t][g=ph*8+fb][lane][8]: lane's 16B = V[p][f=fb*32+(lane&31)] with
// p = t*32 + (j&3) + 8*(j>>2) + 4*(lane>>5) + 16*ph   (matches P-reg order)
__global__ __launch_bounds__(256) void k_poolVF(const float* __restrict__ pool,
                                                _Float16* __restrict__ poolVF){
  int t = blockIdx.x >> 2;
  int tid = threadIdx.x;
  int g = ((blockIdx.x & 3) << 2) | (tid >> 6);   // 0-15: ph=g>>3, fb=g&7
  int lane = tid & 63;
  int f = (g & 7)*32 + (lane & 31);
  int ph = g >> 3, h2 = lane >> 5;
  f16x8 o;
  #pragma unroll
  for (int j = 0; j < 8; ++j) {
    int po = (j & 3) + 8*(j >> 2) + 4*h2 + 16*ph;
    o[j] = (_Float16)pool[(size_t)f*POOL_ + t*32 + po];
  }
  *(f16x8*)((char*)poolVF + (size_t)t*16384 + g*1024 + lane*16) = o;
}

// ---------------- x [4][512][4096] f32 -> xT [4][4096][512] bf16 ----------------
__global__ __launch_bounds__(256) void k_xT(const float* __restrict__ x,
                                            unsigned short* __restrict__ xT){
  __shared__ float tile[32][33];
  int b = blockIdx.x;
  int lt = b & 127; int ct = (b >> 7) & 15; int n = b >> 11;
  int t = threadIdx.x;
  int fi = t >> 3, j = (t & 7) * 4;
  const float4 v = *(const float4*)(x + ((size_t)(n*CHN + ct*32 + fi)) * HWD + lt*32 + j);
  tile[fi][j+0] = v.x; tile[fi][j+1] = v.y; tile[fi][j+2] = v.z; tile[fi][j+3] = v.w;
  __syncthreads();
  int pi = t >> 3, fj = (t & 7) * 4;
  ushort4 o;
  o.x = f2bf(tile[fj+0][pi]); o.y = f2bf(tile[fj+1][pi]);
  o.z = f2bf(tile[fj+2][pi]); o.w = f2bf(tile[fj+3][pi]);
  *(ushort4*)((char*)xT + ((size_t)(n*HWD + lt*32 + pi)) * 1024 + (ct*32 + fj) * 2) = o;
}

// ---------------- theta GEMM: Q[l][f] = log2e * sum_c xT[l][c] * wt[f][c] ----
__global__ __launch_bounds__(256) void k_theta(const unsigned short* __restrict__ xT,
                                               const unsigned short* __restrict__ wt,
                                               unsigned short* __restrict__ Q){
  int w = threadIdx.x >> 6, lane = threadIdx.x & 63;
  int lq = lane & 15, hq = lane >> 4;
  int lbase = blockIdx.x * 64 + w * 16;
  const char* xb = (const char*)xT;
  const char* wb = (const char*)wt;
  f32x4 acc[16];
  #pragma unroll
  for (int i = 0; i < 16; ++i) acc[i] = {};
  #pragma unroll 2
  for (int kk = 0; kk < 16; ++kk) {
    bf16x8 a = ld_bf8(xb + (size_t)(lbase + lq) * 1024 + kk*64 + hq*16);
    #pragma unroll
    for (int fi = 0; fi < 16; ++fi) {
      bf16x8 bfr = ld_bf8(wb + (size_t)(fi*16 + lq) * 1024 + kk*64 + hq*16);
      acc[fi] = mfma16(a, bfr, acc[fi]);
    }
  }
  #pragma unroll
  for (int fi = 0; fi < 16; ++fi) {
    #pragma unroll
    for (int r = 0; r < 4; ++r) {
      int l = lbase + hq*4 + r;
      Q[(size_t)l * 256 + fi*16 + lq] = f2bf(acc[fi][r] * 1.44269504f);
    }
  }
}

// ---------------- fused flash attention over the concept pool ----------------
// Grid 512 = 128 q-blocks x 4 slices; block 256 thr = 4 waves x 32 q-rows.
// ROTATED 2-phase pipeline: PV(t-1) at the top of iter t overlaps with
// stage(t+1) issue and QK^T(t) (independent MFMA clusters). One __syncthreads
// per tile (verified template). K 2-deep, V 3-deep (PV lags one tile).
// Rescale/epilogue broadcast via __shfl (no LDS); LDS = 80 KB = 2 blocks/CU.
__global__ __launch_bounds__(256, 2) void k_attn(const unsigned short* __restrict__ Qg,
                                                 const unsigned short* __restrict__ poolKF,
                                                 const _Float16* __restrict__ poolVF,
                                                 _Float16* __restrict__ accP,
                                                 float* __restrict__ pm,
                                                 float* __restrict__ ps){
  __shared__ __attribute__((aligned(16))) unsigned short K_lds[2][32*256]; // 32 KB
  __shared__ __attribute__((aligned(16))) _Float16 V_lds[3][8192];         // 48 KB

  int w = threadIdx.x >> 6, lane = threadIdx.x & 63;
  int ln = lane & 31, h2 = lane >> 5;
  int qblock = blockIdx.x & 127, slice = blockIdx.x >> 7;
  int qa0 = qblock * 128 + w * 32;

  // Q as B-fragments for swapped QK^T: col=q=ln, k=(h2)*8+j per 16-k chunk
  const char* qp = (const char*)Qg;
  bf16x8 qf[16];
  #pragma unroll
  for (int kc = 0; kc < 16; ++kc)
    qf[kc] = ld_bf8(qp + (size_t)(qa0 + ln) * 512 + kc*32 + h2*16);

  f32x16 acc32[8];
  #pragma unroll
  for (int i = 0; i < 8; ++i) acc32[i] = {};
  float accs = 0.0f;                       // running rowsum for q = ln
  float m = -__builtin_inff();             // running max (log2 domain), q = ln
  f16x8 pa0 = {}, pa1 = {};                // P fragments of previous tile

  const char* ktb = (const char*)poolKF;
  const char* vnb = (const char*)poolVF;
  int kds[4];
  #pragma unroll
  for (int i = 0; i < 4; ++i) kds[i] = (w*4 + i) * 1024;
  int lsrc = lane * 16;

  // prologue: stage tile 0 into K[0], V[0]
  {
    size_t tb = (size_t)(slice * 64) * 16384;
    #pragma unroll
    for (int i = 0; i < 4; ++i) {
      gload16(ktb + tb + kds[i] + lsrc, (char*)K_lds[0] + kds[i]);
      gload16(vnb + tb + kds[i] + lsrc, (char*)V_lds[0] + kds[i]);
    }
  }
  __syncthreads();

  for (int t = 0; t < 64; ++t) {
    // PV(t-1): independent of QK^T(t) -> scheduler interleaves both clusters
    if (t > 0) {
      const char* Vb = (const char*)V_lds[(t-1)%3] + lsrc;
      #pragma unroll
      for (int fb = 0; fb < 8; ++fb)
        acc32[fb] = mfma32h(pa0, ld_f8(Vb + fb*1024), acc32[fb]);
      #pragma unroll
      for (int fb = 0; fb < 8; ++fb)
        acc32[fb] = mfma32h(pa1, ld_f8(Vb + (8 + fb)*1024), acc32[fb]);
    }

    // STAGE(t+1): K into 2-deep, V into 3-deep ring
    if (t < 63) {
      size_t tb = (size_t)(slice*64 + t + 1) * 16384;
      char* Kd = (char*)K_lds[(t+1) & 1];
      char* Vd = (char*)V_lds[(t+1) % 3];
      #pragma unroll
      for (int i = 0; i < 4; ++i) {
        gload16(ktb + tb + kds[i] + lsrc, Kd + kds[i]);
        gload16(vnb + tb + kds[i] + lsrc, Vd + kds[i]);
      }
    }

    // S^T = K @ Q^T via mfma32 (A=K rows=p, B=Q cols=q): lane ln holds
    // S[p=(r&3)+8*(r>>2)+4*h2][q=ln] in regs r=0..15.
    const char* Kb = (const char*)K_lds[t & 1] + lsrc;
    f32x16 Sa = {}, Sb = {};
    #pragma unroll
    for (int kc = 0; kc < 8; ++kc) {
      bf16x8 k0 = ld_bf8(Kb + (2*kc)*1024);
      bf16x8 k1 = ld_bf8(Kb + (2*kc+1)*1024);
      Sa = mfma32b(k0, qf[2*kc], Sa);
      Sb = mfma32b(k1, qf[2*kc+1], Sb);
    }
    float S[16];
    #pragma unroll
    for (int r = 0; r < 16; ++r) S[r] = Sa[r] + Sb[r];

    // lane-local softmax (q = ln): pairwise max tree + cross-half swap
    float x0 = fmaxf(S[0], S[1]),  x1 = fmaxf(S[2], S[3]);
    float x2 = fmaxf(S[4], S[5]),  x3 = fmaxf(S[6], S[7]);
    float x4 = fmaxf(S[8], S[9]),  x5 = fmaxf(S[10], S[11]);
    float x6 = fmaxf(S[12], S[13]), x7 = fmaxf(S[14], S[15]);
    float px = fmaxf(fmaxf(fmaxf(x0, x1), fmaxf(x2, x3)),
                     fmaxf(fmaxf(x4, x5), fmaxf(x6, x7)));
    px = fmaxf(px, __shfl_xor(px, 32));

    // defer-max: rescale only when max grows by > 5.5 (log2 units);
    // per-q scale gathered via shfl (sc for q lives at lane q / q+32)
    if (__any((int)(px > m + 5.5f))) {
      float mn = fmaxf(m, px);
      float sc = fexp2(m - mn);
      m = mn;
      accs *= sc;
      #pragma unroll
      for (int r = 0; r < 16; ++r) {
        int qsrc = (r & 3) + 8*(r >> 2) + 4*h2 + (lane & 32);
        float s = __shfl(sc, qsrc);
        #pragma unroll
        for (int fb = 0; fb < 8; ++fb) acc32[fb][r] *= s;
      }
    }

    // P = exp2(S - m) in-register + rowsum; pack into PV A-fragments
    float Pr[16];
    #pragma unroll
    for (int r = 0; r < 16; ++r) Pr[r] = fexp2(S[r] - m);
    float sum = (((Pr[0]+Pr[1])+(Pr[2]+Pr[3])) + ((Pr[4]+Pr[5])+(Pr[6]+Pr[7])))
              + (((Pr[8]+Pr[9])+(Pr[10]+Pr[11])) + ((Pr[12]+Pr[13])+(Pr[14]+Pr[15])));
    sum += __shfl_xor(sum, 32);
    accs += sum;
    u32x4 w0, w1;
    #pragma unroll
    for (int j = 0; j < 4; ++j) {
      w0[j] = pk_f16(Pr[2*j],   Pr[2*j+1]);
      w1[j] = pk_f16(Pr[8+2*j], Pr[8+2*j+1]);
    }
    pa0 = __builtin_bit_cast(f16x8, w0);
    pa1 = __builtin_bit_cast(f16x8, w1);

    __syncthreads();   // tile t+1 staged by all waves; rings safe to advance
  }

  // PV(63): last tile's P against V[63%3]
  {
    const char* Vb = (const char*)V_lds[63 % 3] + lsrc;
    #pragma unroll
    for (int fb = 0; fb < 8; ++fb)
      acc32[fb] = mfma32h(pa0, ld_f8(Vb + fb*1024), acc32[fb]);
    #pragma unroll
    for (int fb = 0; fb < 8; ++fb)
      acc32[fb] = mfma32h(pa1, ld_f8(Vb + (8 + fb)*1024), acc32[fb]);
  }

  // ---- epilogue: per-slice normalized output (f16) + (m, rowsum) ----
  float inv[16];
  #pragma unroll
  for (int r = 0; r < 16; ++r) {
    int qsrc = (r & 3) + 8*(r >> 2) + 4*h2 + (lane & 32);
    inv[r] = 1.0f / __shfl(accs, qsrc);
  }
  size_t sbase = (size_t)slice * 16384 + qa0;
  #pragma unroll
  for (int fb = 0; fb < 8; ++fb) {
    #pragma unroll
    for (int r = 0; r < 16; ++r) {
      int q = (r & 3) + 8*(r >> 2) + 4*h2;
      accP[(sbase + q) * 256 + fb*32 + ln] = (_Float16)(acc32[fb][r] * inv[r]);
    }
  }
  if (lane < 32) {            // per-q scalars live at lane q
    pm[sbase + lane] = m;     // log2-domain running max
    ps[sbase + lane] = accs;  // rowsum
  }
}

// ---------------- combine the 4 pool-slice partials (pre-normalized, log2 m) --
__global__ __launch_bounds__(256) void k_comb(const _Float16* __restrict__ accP,
                                              const float* __restrict__ pm,
                                              const float* __restrict__ ps,
                                              unsigned short* __restrict__ agg){
  int q = blockIdx.x * 16 + (threadIdx.x >> 4);
  int f0 = (threadIdx.x & 15) * 16;
  float m0 = pm[q], m1 = pm[16384 + q], m2 = pm[2*16384 + q], m3 = pm[3*16384 + q];
  float M = fmaxf(fmaxf(m0, m1), fmaxf(m2, m3));
  float w0 = fexp2(m0 - M) * ps[q];
  float w1 = fexp2(m1 - M) * ps[16384 + q];
  float w2 = fexp2(m2 - M) * ps[2*16384 + q];
  float w3 = fexp2(m3 - M) * ps[3*16384 + q];
  float inv = 1.0f / (w0 + w1 + w2 + w3);
  w0 *= inv; w1 *= inv; w2 *= inv; w3 *= inv;
  const _Float16* a0 = accP + (size_t)q * 256 + f0;
  #pragma unroll
  for (int j = 0; j < 16; j += 8) {
    f16x8 v0 = *(const f16x8*)(a0 + j);
    f16x8 v1 = *(const f16x8*)(a0 + j + (size_t)16384*256);
    f16x8 v2 = *(const f16x8*)(a0 + j + (size_t)2*16384*256);
    f16x8 v3 = *(const f16x8*)(a0 + j + (size_t)3*16384*256);
    u16x8 o;
    #pragma unroll
    for (int k = 0; k < 8; ++k) {
      float s = w0*(float)v0[k] + w1*(float)v1[k] + w2*(float)v2[k] + w3*(float)v3[k];
      o[k] = f2bf(s);
    }
    *(u16x8*)(agg + (size_t)q * 256 + f0 + j) = o;
  }
}

// ---------------- output GEMM + gated residual ----------------
__global__ __launch_bounds__(256) void k_out(const float* __restrict__ x,
                                             const unsigned short* __restrict__ wo,
                                             const unsigned short* __restrict__ agg,
                                             const float* __restrict__ gammap,
                                             float* __restrict__ out){
  int w = threadIdx.x >> 6, lane = threadIdx.x & 63;
  int lq = lane & 15, hq = lane >> 4;
  int b = blockIdx.x;
  int lg = b & 63, cg = (b >> 6) & 7, n = b >> 9;
  const char* wb = (const char*)wo;
  const char* ab = (const char*)agg;
  f32x4 acc[4];
  #pragma unroll
  for (int i = 0; i < 4; ++i) acc[i] = {};
  int crow = cg*64 + w*16 + lq;
  #pragma unroll
  for (int kk = 0; kk < 8; ++kk) {
    bf16x8 a = ld_bf8(wb + (size_t)crow * 512 + kk*64 + hq*16);
    #pragma unroll
    for (int li = 0; li < 4; ++li) {
      bf16x8 bb = ld_bf8(ab + (size_t)(n*HWD + lg*64 + li*16 + lq) * 512 + kk*64 + hq*16);
      acc[li] = mfma16(a, bb, acc[li]);
    }
  }
  float g = gammap[0];
  #pragma unroll
  for (int li = 0; li < 4; ++li) {
    #pragma unroll
    for (int r = 0; r < 4; ++r) {
      int c = cg*64 + w*16 + hq*4 + r;
      int l = lg*64 + li*16 + lq;
      size_t idx = ((size_t)(n*CHN + c)) * HWD + l;
      out[idx] = x[idx] + g * acc[li][r];
    }
  }
}

extern "C" void kernel_launch(void* const* d_in, const int* in_sizes, int n_in,
                              void* d_out, int out_size, void* d_ws, size_t ws_size,
                              hipStream_t stream) {
  const float* x     = (const float*)d_in[0];
  const float* wt    = (const float*)d_in[1];
  const float* wo    = (const float*)d_in[2];
  const float* pool  = (const float*)d_in[3];
  const float* gamma = (const float*)d_in[4];
  char* ws = (char*)d_ws;
  unsigned short* wt_b  = (unsigned short*)(ws + 0);         // 256 KB
  unsigned short* wo_b  = (unsigned short*)(ws + 262144);    // 256 KB
  _Float16*       poolVF= (_Float16*)(ws + 524288);          // 4 MB (fragment-major f16)
  unsigned short* poolKF= (unsigned short*)(ws + 4718592);   // 4 MB (fragment-major bf16)
  unsigned short* Qb    = (unsigned short*)(ws + 8912896);   // 8 MB
  unsigned short* aggb  = (unsigned short*)(ws + 17301504);  // 8 MB
  unsigned short* xT    = (unsigned short*)(ws + 25690112);  // 16 MB (dead after k_theta)
  _Float16*       accP  = (_Float16*)(ws + 25690112);        // 32 MB (overlaps dead xT)
  float*          pm    = (float*)(ws + 59244544);           // 256 KB
  float*          ps    = (float*)(ws + 59506688);           // 256 KB
  float* out = (float*)d_out;

  k_cvt<<<dim3(128), dim3(256), 0, stream>>>(wt, wt_b, 32768);
  k_cvt<<<dim3(128), dim3(256), 0, stream>>>(wo, wo_b, 32768);
  k_poolVF<<<dim3(1024), dim3(256), 0, stream>>>(pool, poolVF);
  k_poolKF<<<dim3(1024), dim3(256), 0, stream>>>(pool, poolKF);
  k_xT<<<dim3(8192), dim3(256), 0, stream>>>(x, xT);
  k_theta<<<dim3(256), dim3(256), 0, stream>>>(xT, wt_b, Qb);
  k_attn<<<dim3(512), dim3(256), 0, stream>>>(Qb, poolKF, poolVF, accP, pm, ps);
  k_comb<<<dim3(1024), dim3(256), 0, stream>>>(accP, pm, ps, aggb);
  k_out<<<dim3(2048), dim3(256), 0, stream>>>(x, wo_b, aggb, gamma, out);
}

// Round 14
// 248.495 us; speedup vs baseline: 1.0228x; 1.0228x over previous
//
#include <hip/hip_runtime.h>

#define NB 4
#define CHN 512
#define HWD 4096
#define LTOT (NB*HWD)
#define FEAT_ 256
#define POOL_ 8192

typedef __attribute__((ext_vector_type(8))) __bf16 bf16x8;
typedef __attribute__((ext_vector_type(8))) unsigned short u16x8;
typedef __attribute__((ext_vector_type(8))) _Float16 f16x8;
typedef __attribute__((ext_vector_type(4))) unsigned u32x4;
typedef __attribute__((ext_vector_type(4))) float f32x4;
typedef __attribute__((ext_vector_type(16))) float f32x16;

static __device__ __forceinline__ float fexp2(float x){
  return __builtin_amdgcn_exp2f(x);   // raw v_exp_f32 (2^x)
}

static __device__ __forceinline__ unsigned short f2bf(float f){
  union { float f; unsigned u; } c; c.f = f;
  unsigned u = c.u;
  u += 0x7fffu + ((u >> 16) & 1u);   // round-to-nearest-even
  return (unsigned short)(u >> 16);
}

static __device__ __forceinline__ unsigned pk_f16(float lo, float hi){
  auto r = __builtin_amdgcn_cvt_pkrtz(lo, hi);   // __fp16 ext_vector(2)
  return __builtin_bit_cast(unsigned, r);        // [15:0]=f16(lo), [31:16]=f16(hi)
}

static __device__ __forceinline__ f32x4 mfma16(bf16x8 a, bf16x8 b, f32x4 c){
  return __builtin_amdgcn_mfma_f32_16x16x32_bf16(a, b, c, 0, 0, 0);
}
static __device__ __forceinline__ f32x16 mfma32b(bf16x8 a, bf16x8 b, f32x16 c){
  return __builtin_amdgcn_mfma_f32_32x32x16_bf16(a, b, c, 0, 0, 0);
}
static __device__ __forceinline__ f32x16 mfma32h(f16x8 a, f16x8 b, f32x16 c){
  return __builtin_amdgcn_mfma_f32_32x32x16_f16(a, b, c, 0, 0, 0);
}

static __device__ __forceinline__ bf16x8 ld_bf8(const void* p){
  u16x8 v = *(const u16x8*)p;
  return __builtin_bit_cast(bf16x8, v);
}
static __device__ __forceinline__ f16x8 ld_f8(const void* p){
  u16x8 v = *(const u16x8*)p;
  return __builtin_bit_cast(f16x8, v);
}

static __device__ __forceinline__ void gload16(const void* g, void* l){
  __builtin_amdgcn_global_load_lds((const __attribute__((address_space(1))) void*)g,
                                   (__attribute__((address_space(3))) void*)l, 16, 0, 0);
}

// ---------------- f32 -> bf16 convert (layout-preserving) ----------------
__global__ void k_cvt(const float* __restrict__ src, unsigned short* __restrict__ dst, int n4){
  int i = blockIdx.x * 256 + threadIdx.x;
  if (i < n4) {
    const float4 v = *(const float4*)(src + (size_t)i * 4);
    ushort4 o; o.x = f2bf(v.x); o.y = f2bf(v.y); o.z = f2bf(v.z); o.w = f2bf(v.w);
    *(ushort4*)(dst + (size_t)i * 4) = o;
  }
}

// ---------------- pool -> poolKF: A-fragment-major K (bf16, swapped QK^T) ----
// poolKF[t][kc][lane][8]: lane's 16B = K[p = t*32 + (lane&31)]
//                                       [f = kc*16 + (lane>>5)*8 + j]
__global__ __launch_bounds__(256) void k_poolKF(const float* __restrict__ pool,
                                                unsigned short* __restrict__ poolKF){
  int t = blockIdx.x >> 2;
  int tid = threadIdx.x;
  int kc = ((blockIdx.x & 3) << 2) | (tid >> 6);
  int lane = tid & 63;
  int p = t*32 + (lane & 31);
  int f0 = kc*16 + (lane >> 5)*8;
  u16x8 o;
  #pragma unroll
  for (int j = 0; j < 8; ++j) o[j] = f2bf(pool[(size_t)(f0+j)*POOL_ + p]);
  *(u16x8*)((char*)poolKF + (size_t)t*16384 + kc*1024 + lane*16) = o;
}

// ---------------- pool -> poolVF: B-fragment-major V (f16, reg-order sigma) --
// poolVF[t][g=ph*8+fb][lane][8]: lane's 16B = V[p][f=fb*32+(lane&31)] with
// p = t*32 + (j&3) + 8*(j>>2) + 4*(lane>>5) + 16*ph   (matches P-reg order)
__global__ __launch_bounds__(256) void k_poolVF(const float* __restrict__ pool,
                                                _Float16* __restrict__ poolVF){
  int t = blockIdx.x >> 2;
  int tid = threadIdx.x;
  int g = ((blockIdx.x & 3) << 2) | (tid >> 6);   // 0-15: ph=g>>3, fb=g&7
  int lane = tid & 63;
  int f = (g & 7)*32 + (lane & 31);
  int ph = g >> 3, h2 = lane >> 5;
  f16x8 o;
  #pragma unroll
  for (int j = 0; j < 8; ++j) {
    int po = (j & 3) + 8*(j >> 2) + 4*h2 + 16*ph;
    o[j] = (_Float16)pool[(size_t)f*POOL_ + t*32 + po];
  }
  *(f16x8*)((char*)poolVF + (size_t)t*16384 + g*1024 + lane*16) = o;
}

// ---------------- x [4][512][4096] f32 -> xT [4][4096][512] bf16 ----------------
__global__ __launch_bounds__(256) void k_xT(const float* __restrict__ x,
                                            unsigned short* __restrict__ xT){
  __shared__ float tile[32][33];
  int b = blockIdx.x;
  int lt = b & 127; int ct = (b >> 7) & 15; int n = b >> 11;
  int t = threadIdx.x;
  int fi = t >> 3, j = (t & 7) * 4;
  const float4 v = *(const float4*)(x + ((size_t)(n*CHN + ct*32 + fi)) * HWD + lt*32 + j);
  tile[fi][j+0] = v.x; tile[fi][j+1] = v.y; tile[fi][j+2] = v.z; tile[fi][j+3] = v.w;
  __syncthreads();
  int pi = t >> 3, fj = (t & 7) * 4;
  ushort4 o;
  o.x = f2bf(tile[fj+0][pi]); o.y = f2bf(tile[fj+1][pi]);
  o.z = f2bf(tile[fj+2][pi]); o.w = f2bf(tile[fj+3][pi]);
  *(ushort4*)((char*)xT + ((size_t)(n*HWD + lt*32 + pi)) * 1024 + (ct*32 + fj) * 2) = o;
}

// ---------------- theta GEMM: Q[l][f] = log2e * sum_c xT[l][c] * wt[f][c] ----
__global__ __launch_bounds__(256) void k_theta(const unsigned short* __restrict__ xT,
                                               const unsigned short* __restrict__ wt,
                                               unsigned short* __restrict__ Q){
  int w = threadIdx.x >> 6, lane = threadIdx.x & 63;
  int lq = lane & 15, hq = lane >> 4;
  int lbase = blockIdx.x * 64 + w * 16;
  const char* xb = (const char*)xT;
  const char* wb = (const char*)wt;
  f32x4 acc[16];
  #pragma unroll
  for (int i = 0; i < 16; ++i) acc[i] = {};
  #pragma unroll 2
  for (int kk = 0; kk < 16; ++kk) {
    bf16x8 a = ld_bf8(xb + (size_t)(lbase + lq) * 1024 + kk*64 + hq*16);
    #pragma unroll
    for (int fi = 0; fi < 16; ++fi) {
      bf16x8 bfr = ld_bf8(wb + (size_t)(fi*16 + lq) * 1024 + kk*64 + hq*16);
      acc[fi] = mfma16(a, bfr, acc[fi]);
    }
  }
  #pragma unroll
  for (int fi = 0; fi < 16; ++fi) {
    #pragma unroll
    for (int r = 0; r < 4; ++r) {
      int l = lbase + hq*4 + r;
      Q[(size_t)l * 256 + fi*16 + lq] = f2bf(acc[fi][r] * 1.44269504f);
    }
  }
}

// ---------------- fused flash attention over the concept pool ----------------
// Grid 512 = 128 q-blocks x 4 slices; block 256 thr = 4 waves x 32 q-rows.
// R12 structure (replay-stable, 149.5us): 2-phase pipeline STAGE(t+1) ->
// compute(t) -> __syncthreads(). Swapped QK^T (S^T = mfma32(K,Q)), lane-local
// softmax, in-register P. + T5: s_setprio(1) around MFMA clusters (2 blocks/CU
// at uncorrelated phases -> scheduler favors MFMA-issuing waves).
__global__ __launch_bounds__(256, 2) void k_attn(const unsigned short* __restrict__ Qg,
                                                 const unsigned short* __restrict__ poolKF,
                                                 const _Float16* __restrict__ poolVF,
                                                 _Float16* __restrict__ accP,
                                                 float* __restrict__ pm,
                                                 float* __restrict__ ps){
  __shared__ __attribute__((aligned(16))) unsigned short K_lds[2][32*256]; // 32 KB
  __shared__ __attribute__((aligned(16))) _Float16 V_lds[2][8192];         // 32 KB
  __shared__ float Sc[4][32];
  __shared__ float As[4][32];

  int w = threadIdx.x >> 6, lane = threadIdx.x & 63;
  int ln = lane & 31, h2 = lane >> 5;
  int qblock = blockIdx.x & 127, slice = blockIdx.x >> 7;
  int qa0 = qblock * 128 + w * 32;

  // Q as B-fragments for swapped QK^T: col=q=ln, k=(h2)*8+j per 16-k chunk
  const char* qp = (const char*)Qg;
  bf16x8 qf[16];
  #pragma unroll
  for (int kc = 0; kc < 16; ++kc)
    qf[kc] = ld_bf8(qp + (size_t)(qa0 + ln) * 512 + kc*32 + h2*16);

  f32x16 acc32[8];
  #pragma unroll
  for (int i = 0; i < 8; ++i) acc32[i] = {};
  float accs = 0.0f;                       // running rowsum for q = ln
  float m = -__builtin_inff();             // running max (log2 domain), q = ln

  const char* ktb = (const char*)poolKF;
  const char* vnb = (const char*)poolVF;
  int kds[4];
  #pragma unroll
  for (int i = 0; i < 4; ++i) kds[i] = (w*4 + i) * 1024;
  int lsrc = lane * 16;

  // prologue: stage tile 0 into buffer 0
  {
    size_t tb = (size_t)(slice * 64) * 16384;
    #pragma unroll
    for (int i = 0; i < 4; ++i) {
      gload16(ktb + tb + kds[i] + lsrc, (char*)K_lds[0] + kds[i]);
      gload16(vnb + tb + kds[i] + lsrc, (char*)V_lds[0] + kds[i]);
    }
  }
  __syncthreads();

  int cur = 0;
  for (int t = 0; t < 64; ++t) {
    if (t < 63) {
      size_t tb = (size_t)(slice*64 + t + 1) * 16384;
      #pragma unroll
      for (int i = 0; i < 4; ++i) {
        gload16(ktb + tb + kds[i] + lsrc, (char*)K_lds[cur^1] + kds[i]);
        gload16(vnb + tb + kds[i] + lsrc, (char*)V_lds[cur^1] + kds[i]);
      }
    }

    const char* Kb = (const char*)K_lds[cur] + lsrc;
    const char* Vb = (const char*)V_lds[cur] + lsrc;

    // S^T = K @ Q^T via mfma32 (A=K rows=p, B=Q cols=q): lane ln holds
    // S[p=(r&3)+8*(r>>2)+4*h2][q=ln] in regs r=0..15. Two interleaved chains.
    f32x16 Sa = {}, Sb = {};
    __builtin_amdgcn_s_setprio(1);
    #pragma unroll
    for (int kc = 0; kc < 8; ++kc) {
      bf16x8 k0 = ld_bf8(Kb + (2*kc)*1024);
      bf16x8 k1 = ld_bf8(Kb + (2*kc+1)*1024);
      Sa = mfma32b(k0, qf[2*kc], Sa);
      Sb = mfma32b(k1, qf[2*kc+1], Sb);
    }
    __builtin_amdgcn_s_setprio(0);
    float S[16];
    #pragma unroll
    for (int r = 0; r < 16; ++r) S[r] = Sa[r] + Sb[r];

    // lane-local softmax (q = ln): in-lane max over 16 + cross-half swap
    float px = S[0];
    #pragma unroll
    for (int r = 1; r < 16; ++r) px = fmaxf(px, S[r]);
    px = fmaxf(px, __shfl_xor(px, 32));

    // defer-max: rescale only when max grows by > 5.5 (log2 units)
    if (__any((int)(px > m + 5.5f))) {
      float mn = fmaxf(m, px);
      float sc = fexp2(m - mn);
      m = mn;
      accs *= sc;
      if (lane < 32) Sc[w][lane] = sc;   // broadcast per-q scale to all lanes
      f32x4 s4[4];
      #pragma unroll
      for (int blk = 0; blk < 4; ++blk)
        s4[blk] = *(const f32x4*)&Sc[w][8*blk + 4*h2];
      #pragma unroll
      for (int fb = 0; fb < 8; ++fb)
        #pragma unroll
        for (int r = 0; r < 16; ++r)
          acc32[fb][r] *= s4[r>>2][r&3];
    }

    // P = exp2(S - m) in-register + rowsum; pack into PV A-fragments
    float Pr[16];
    #pragma unroll
    for (int r = 0; r < 16; ++r) Pr[r] = fexp2(S[r] - m);
    float sum = (((Pr[0]+Pr[1])+(Pr[2]+Pr[3])) + ((Pr[4]+Pr[5])+(Pr[6]+Pr[7])))
              + (((Pr[8]+Pr[9])+(Pr[10]+Pr[11])) + ((Pr[12]+Pr[13])+(Pr[14]+Pr[15])));
    sum += __shfl_xor(sum, 32);
    accs += sum;
    u32x4 w0, w1;
    #pragma unroll
    for (int j = 0; j < 4; ++j) {
      w0[j] = pk_f16(Pr[2*j],   Pr[2*j+1]);
      w1[j] = pk_f16(Pr[8+2*j], Pr[8+2*j+1]);
    }
    f16x8 pa0 = __builtin_bit_cast(f16x8, w0);
    f16x8 pa1 = __builtin_bit_cast(f16x8, w1);

    // PV via mfma32h: A = packed P (row=q=ln, k per poolVF sigma), B = V frags
    __builtin_amdgcn_s_setprio(1);
    #pragma unroll
    for (int fb = 0; fb < 8; ++fb) {
      f16x8 v0 = ld_f8(Vb + fb*1024);
      acc32[fb] = mfma32h(pa0, v0, acc32[fb]);
    }
    #pragma unroll
    for (int fb = 0; fb < 8; ++fb) {
      f16x8 v1 = ld_f8(Vb + (8 + fb)*1024);
      acc32[fb] = mfma32h(pa1, v1, acc32[fb]);
    }
    __builtin_amdgcn_s_setprio(0);

    __syncthreads();   // tile t+1 staged by all waves; buf cur free for t+2
    cur ^= 1;
  }

  // ---- epilogue: per-slice normalized output (f16) + (m, rowsum) ----
  if (lane < 32) As[w][lane] = accs;
  float inv[16];
  #pragma unroll
  for (int blk = 0; blk < 4; ++blk) {
    f32x4 a4 = *(const f32x4*)&As[w][8*blk + 4*h2];
    inv[blk*4+0] = 1.0f / a4[0]; inv[blk*4+1] = 1.0f / a4[1];
    inv[blk*4+2] = 1.0f / a4[2]; inv[blk*4+3] = 1.0f / a4[3];
  }
  size_t sbase = (size_t)slice * 16384 + qa0;
  #pragma unroll
  for (int fb = 0; fb < 8; ++fb) {
    #pragma unroll
    for (int r = 0; r < 16; ++r) {
      int q = (r & 3) + 8*(r >> 2) + 4*h2;
      accP[(sbase + q) * 256 + fb*32 + ln] = (_Float16)(acc32[fb][r] * inv[r]);
    }
  }
  if (lane < 32) {            // per-q scalars live at lane q
    pm[sbase + lane] = m;     // log2-domain running max
    ps[sbase + lane] = accs;  // rowsum
  }
}

// ---------------- combine the 4 pool-slice partials (pre-normalized, log2 m) --
__global__ __launch_bounds__(256) void k_comb(const _Float16* __restrict__ accP,
                                              const float* __restrict__ pm,
                                              const float* __restrict__ ps,
                                              unsigned short* __restrict__ agg){
  int q = blockIdx.x * 16 + (threadIdx.x >> 4);
  int f0 = (threadIdx.x & 15) * 16;
  float m0 = pm[q], m1 = pm[16384 + q], m2 = pm[2*16384 + q], m3 = pm[3*16384 + q];
  float M = fmaxf(fmaxf(m0, m1), fmaxf(m2, m3));
  float w0 = fexp2(m0 - M) * ps[q];
  float w1 = fexp2(m1 - M) * ps[16384 + q];
  float w2 = fexp2(m2 - M) * ps[2*16384 + q];
  float w3 = fexp2(m3 - M) * ps[3*16384 + q];
  float inv = 1.0f / (w0 + w1 + w2 + w3);
  w0 *= inv; w1 *= inv; w2 *= inv; w3 *= inv;
  const _Float16* a0 = accP + (size_t)q * 256 + f0;
  #pragma unroll
  for (int j = 0; j < 16; j += 8) {
    f16x8 v0 = *(const f16x8*)(a0 + j);
    f16x8 v1 = *(const f16x8*)(a0 + j + (size_t)16384*256);
    f16x8 v2 = *(const f16x8*)(a0 + j + (size_t)2*16384*256);
    f16x8 v3 = *(const f16x8*)(a0 + j + (size_t)3*16384*256);
    u16x8 o;
    #pragma unroll
    for (int k = 0; k < 8; ++k) {
      float s = w0*(float)v0[k] + w1*(float)v1[k] + w2*(float)v2[k] + w3*(float)v3[k];
      o[k] = f2bf(s);
    }
    *(u16x8*)(agg + (size_t)q * 256 + f0 + j) = o;
  }
}

// ---------------- output GEMM + gated residual ----------------
__global__ __launch_bounds__(256) void k_out(const float* __restrict__ x,
                                             const unsigned short* __restrict__ wo,
                                             const unsigned short* __restrict__ agg,
                                             const float* __restrict__ gammap,
                                             float* __restrict__ out){
  int w = threadIdx.x >> 6, lane = threadIdx.x & 63;
  int lq = lane & 15, hq = lane >> 4;
  int b = blockIdx.x;
  int lg = b & 63, cg = (b >> 6) & 7, n = b >> 9;
  const char* wb = (const char*)wo;
  const char* ab = (const char*)agg;
  f32x4 acc[4];
  #pragma unroll
  for (int i = 0; i < 4; ++i) acc[i] = {};
  int crow = cg*64 + w*16 + lq;
  #pragma unroll
  for (int kk = 0; kk < 8; ++kk) {
    bf16x8 a = ld_bf8(wb + (size_t)crow * 512 + kk*64 + hq*16);
    #pragma unroll
    for (int li = 0; li < 4; ++li) {
      bf16x8 bb = ld_bf8(ab + (size_t)(n*HWD + lg*64 + li*16 + lq) * 512 + kk*64 + hq*16);
      acc[li] = mfma16(a, bb, acc[li]);
    }
  }
  float g = gammap[0];
  #pragma unroll
  for (int li = 0; li < 4; ++li) {
    #pragma unroll
    for (int r = 0; r < 4; ++r) {
      int c = cg*64 + w*16 + hq*4 + r;
      int l = lg*64 + li*16 + lq;
      size_t idx = ((size_t)(n*CHN + c)) * HWD + l;
      out[idx] = x[idx] + g * acc[li][r];
    }
  }
}

extern "C" void kernel_launch(void* const* d_in, const int* in_sizes, int n_in,
                              void* d_out, int out_size, void* d_ws, size_t ws_size,
                              hipStream_t stream) {
  const float* x     = (const float*)d_in[0];
  const float* wt    = (const float*)d_in[1];
  const float* wo    = (const float*)d_in[2];
  const float* pool  = (const float*)d_in[3];
  const float* gamma = (const float*)d_in[4];
  char* ws = (char*)d_ws;
  unsigned short* wt_b  = (unsigned short*)(ws + 0);         // 256 KB
  unsigned short* wo_b  = (unsigned short*)(ws + 262144);    // 256 KB
  _Float16*       poolVF= (_Float16*)(ws + 524288);          // 4 MB (fragment-major f16)
  unsigned short* poolKF= (unsigned short*)(ws + 4718592);   // 4 MB (fragment-major bf16)
  unsigned short* Qb    = (unsigned short*)(ws + 8912896);   // 8 MB
  unsigned short* aggb  = (unsigned short*)(ws + 17301504);  // 8 MB
  unsigned short* xT    = (unsigned short*)(ws + 25690112);  // 16 MB (dead after k_theta)
  _Float16*       accP  = (_Float16*)(ws + 25690112);        // 32 MB (overlaps dead xT)
  float*          pm    = (float*)(ws + 59244544);           // 256 KB
  float*          ps    = (float*)(ws + 59506688);           // 256 KB
  float* out = (float*)d_out;

  k_cvt<<<dim3(128), dim3(256), 0, stream>>>(wt, wt_b, 32768);
  k_cvt<<<dim3(128), dim3(256), 0, stream>>>(wo, wo_b, 32768);
  k_poolVF<<<dim3(1024), dim3(256), 0, stream>>>(pool, poolVF);
  k_poolKF<<<dim3(1024), dim3(256), 0, stream>>>(pool, poolKF);
  k_xT<<<dim3(8192), dim3(256), 0, stream>>>(x, xT);
  k_theta<<<dim3(256), dim3(256), 0, stream>>>(xT, wt_b, Qb);
  k_attn<<<dim3(512), dim3(256), 0, stream>>>(Qb, poolKF, poolVF, accP, pm, ps);
  k_comb<<<dim3(1024), dim3(256), 0, stream>>>(accP, pm, ps, aggb);
  k_out<<<dim3(2048), dim3(256), 0, stream>>>(x, wo_b, aggb, gamma, out);
}

// Round 15
// 243.570 us; speedup vs baseline: 1.0435x; 1.0202x over previous
//
#include <hip/hip_runtime.h>

#define NB 4
#define CHN 512
#define HWD 4096
#define LTOT (NB*HWD)
#define FEAT_ 256
#define POOL_ 8192

typedef __attribute__((ext_vector_type(8))) __bf16 bf16x8;
typedef __attribute__((ext_vector_type(8))) unsigned short u16x8;
typedef __attribute__((ext_vector_type(8))) _Float16 f16x8;
typedef __attribute__((ext_vector_type(4))) unsigned u32x4;
typedef __attribute__((ext_vector_type(4))) float f32x4;
typedef __attribute__((ext_vector_type(16))) float f32x16;

static __device__ __forceinline__ float fexp2(float x){
  return __builtin_amdgcn_exp2f(x);   // raw v_exp_f32 (2^x)
}

static __device__ __forceinline__ unsigned short f2bf(float f){
  union { float f; unsigned u; } c; c.f = f;
  unsigned u = c.u;
  u += 0x7fffu + ((u >> 16) & 1u);   // round-to-nearest-even
  return (unsigned short)(u >> 16);
}

static __device__ __forceinline__ unsigned pk_f16(float lo, float hi){
  auto r = __builtin_amdgcn_cvt_pkrtz(lo, hi);   // __fp16 ext_vector(2)
  return __builtin_bit_cast(unsigned, r);        // [15:0]=f16(lo), [31:16]=f16(hi)
}

static __device__ __forceinline__ f32x4 mfma16(bf16x8 a, bf16x8 b, f32x4 c){
  return __builtin_amdgcn_mfma_f32_16x16x32_bf16(a, b, c, 0, 0, 0);
}
static __device__ __forceinline__ f32x16 mfma32b(bf16x8 a, bf16x8 b, f32x16 c){
  return __builtin_amdgcn_mfma_f32_32x32x16_bf16(a, b, c, 0, 0, 0);
}
static __device__ __forceinline__ f32x16 mfma32h(f16x8 a, f16x8 b, f32x16 c){
  return __builtin_amdgcn_mfma_f32_32x32x16_f16(a, b, c, 0, 0, 0);
}

static __device__ __forceinline__ bf16x8 ld_bf8(const void* p){
  u16x8 v = *(const u16x8*)p;
  return __builtin_bit_cast(bf16x8, v);
}
static __device__ __forceinline__ f16x8 ld_f8(const void* p){
  u16x8 v = *(const u16x8*)p;
  return __builtin_bit_cast(f16x8, v);
}

static __device__ __forceinline__ void gload16(const void* g, void* l){
  __builtin_amdgcn_global_load_lds((const __attribute__((address_space(1))) void*)g,
                                   (__attribute__((address_space(3))) void*)l, 16, 0, 0);
}

// ---------------- wt+wo f32 -> bf16 (merged, layout-preserving) ----------------
__global__ __launch_bounds__(256) void k_cvtw(const float* __restrict__ wt,
                                              const float* __restrict__ wo,
                                              unsigned short* __restrict__ wt_b,
                                              unsigned short* __restrict__ wo_b){
  int i = blockIdx.x * 256 + threadIdx.x;          // 65536 quads total
  const float* src = (i < 32768) ? wt : wo;
  unsigned short* dst = (i < 32768) ? wt_b : wo_b;
  int j = i & 32767;
  const float4 v = *(const float4*)(src + (size_t)j * 4);
  ushort4 o; o.x = f2bf(v.x); o.y = f2bf(v.y); o.z = f2bf(v.z); o.w = f2bf(v.w);
  *(ushort4*)(dst + (size_t)j * 4) = o;
}

// ---------------- pool -> poolKF (bf16 A-frag) + poolVF (f16 B-frag), merged --
// poolKF[t][kc][lane][8]: lane's 16B = K[p=t*32+(lane&31)][f=kc*16+(lane>>5)*8+j]
// poolVF[t][g=ph*8+fb][lane][8]: lane's 16B = V[p][f=fb*32+(lane&31)],
//   p = t*32 + (j&3) + 8*(j>>2) + 4*(lane>>5) + 16*ph  (matches P-reg order)
__global__ __launch_bounds__(256) void k_poolF(const float* __restrict__ pool,
                                               unsigned short* __restrict__ poolKF,
                                               _Float16* __restrict__ poolVF){
  int b = blockIdx.x;
  int tid = threadIdx.x;
  int lane = tid & 63;
  if (b < 1024) {
    int t = b >> 2;
    int kc = ((b & 3) << 2) | (tid >> 6);
    int p = t*32 + (lane & 31);
    int f0 = kc*16 + (lane >> 5)*8;
    u16x8 o;
    #pragma unroll
    for (int j = 0; j < 8; ++j) o[j] = f2bf(pool[(size_t)(f0+j)*POOL_ + p]);
    *(u16x8*)((char*)poolKF + (size_t)t*16384 + kc*1024 + lane*16) = o;
  } else {
    b -= 1024;
    int t = b >> 2;
    int g = ((b & 3) << 2) | (tid >> 6);   // 0-15: ph=g>>3, fb=g&7
    int f = (g & 7)*32 + (lane & 31);
    int ph = g >> 3, h2 = lane >> 5;
    f16x8 o;
    #pragma unroll
    for (int j = 0; j < 8; ++j) {
      int po = (j & 3) + 8*(j >> 2) + 4*h2 + 16*ph;
      o[j] = (_Float16)pool[(size_t)f*POOL_ + t*32 + po];
    }
    *(f16x8*)((char*)poolVF + (size_t)t*16384 + g*1024 + lane*16) = o;
  }
}

// ---------------- x [4][512][4096] f32 -> xT [4][4096][512] bf16 ----------------
__global__ __launch_bounds__(256) void k_xT(const float* __restrict__ x,
                                            unsigned short* __restrict__ xT){
  __shared__ float tile[32][33];
  int b = blockIdx.x;
  int lt = b & 127; int ct = (b >> 7) & 15; int n = b >> 11;
  int t = threadIdx.x;
  int fi = t >> 3, j = (t & 7) * 4;
  const float4 v = *(const float4*)(x + ((size_t)(n*CHN + ct*32 + fi)) * HWD + lt*32 + j);
  tile[fi][j+0] = v.x; tile[fi][j+1] = v.y; tile[fi][j+2] = v.z; tile[fi][j+3] = v.w;
  __syncthreads();
  int pi = t >> 3, fj = (t & 7) * 4;
  ushort4 o;
  o.x = f2bf(tile[fj+0][pi]); o.y = f2bf(tile[fj+1][pi]);
  o.z = f2bf(tile[fj+2][pi]); o.w = f2bf(tile[fj+3][pi]);
  *(ushort4*)((char*)xT + ((size_t)(n*HWD + lt*32 + pi)) * 1024 + (ct*32 + fj) * 2) = o;
}

// ---------------- theta GEMM: Q[l][f] = log2e * sum_c xT[l][c] * wt[f][c] ----
__global__ __launch_bounds__(256) void k_theta(const unsigned short* __restrict__ xT,
                                               const unsigned short* __restrict__ wt,
                                               unsigned short* __restrict__ Q){
  int w = threadIdx.x >> 6, lane = threadIdx.x & 63;
  int lq = lane & 15, hq = lane >> 4;
  int lbase = blockIdx.x * 64 + w * 16;
  const char* xb = (const char*)xT;
  const char* wb = (const char*)wt;
  f32x4 acc[16];
  #pragma unroll
  for (int i = 0; i < 16; ++i) acc[i] = {};
  #pragma unroll 2
  for (int kk = 0; kk < 16; ++kk) {
    bf16x8 a = ld_bf8(xb + (size_t)(lbase + lq) * 1024 + kk*64 + hq*16);
    #pragma unroll
    for (int fi = 0; fi < 16; ++fi) {
      bf16x8 bfr = ld_bf8(wb + (size_t)(fi*16 + lq) * 1024 + kk*64 + hq*16);
      acc[fi] = mfma16(a, bfr, acc[fi]);
    }
  }
  #pragma unroll
  for (int fi = 0; fi < 16; ++fi) {
    #pragma unroll
    for (int r = 0; r < 4; ++r) {
      int l = lbase + hq*4 + r;
      Q[(size_t)l * 256 + fi*16 + lq] = f2bf(acc[fi][r] * 1.44269504f);
    }
  }
}

// ---------------- fused flash attention over the concept pool ----------------
// Grid 512 = 128 q-blocks x 4 slices; block 256 thr = 4 waves x 32 q-rows.
// R12 structure (replay-stable, 149.5us): 2-phase pipeline STAGE(t+1) ->
// compute(t) -> __syncthreads(). Swapped QK^T (S^T = mfma32(K,Q)), lane-local
// softmax, in-register P. NEW: speculative exp2 (Pr from m_old right after S;
// rare-path fixup) removes the max-reduce from the common-path chain.
__global__ __launch_bounds__(256, 2) void k_attn(const unsigned short* __restrict__ Qg,
                                                 const unsigned short* __restrict__ poolKF,
                                                 const _Float16* __restrict__ poolVF,
                                                 _Float16* __restrict__ accP,
                                                 float* __restrict__ pm,
                                                 float* __restrict__ ps){
  __shared__ __attribute__((aligned(16))) unsigned short K_lds[2][32*256]; // 32 KB
  __shared__ __attribute__((aligned(16))) _Float16 V_lds[2][8192];         // 32 KB
  __shared__ float Sc[4][32];
  __shared__ float As[4][32];

  int w = threadIdx.x >> 6, lane = threadIdx.x & 63;
  int ln = lane & 31, h2 = lane >> 5;
  int qblock = blockIdx.x & 127, slice = blockIdx.x >> 7;
  int qa0 = qblock * 128 + w * 32;

  // Q as B-fragments for swapped QK^T: col=q=ln, k=(h2)*8+j per 16-k chunk
  const char* qp = (const char*)Qg;
  bf16x8 qf[16];
  #pragma unroll
  for (int kc = 0; kc < 16; ++kc)
    qf[kc] = ld_bf8(qp + (size_t)(qa0 + ln) * 512 + kc*32 + h2*16);

  f32x16 acc32[8];
  #pragma unroll
  for (int i = 0; i < 8; ++i) acc32[i] = {};
  float accs = 0.0f;                       // running rowsum for q = ln
  float m = 10.0f;                         // running max (log2 domain), finite
                                           // init so speculative exp2 is safe:
                                           // no-rescale => S-m <= 5.5 => Pr<=45

  const char* ktb = (const char*)poolKF;
  const char* vnb = (const char*)poolVF;
  int kds[4];
  #pragma unroll
  for (int i = 0; i < 4; ++i) kds[i] = (w*4 + i) * 1024;
  int lsrc = lane * 16;

  // prologue: stage tile 0 into buffer 0
  {
    size_t tb = (size_t)(slice * 64) * 16384;
    #pragma unroll
    for (int i = 0; i < 4; ++i) {
      gload16(ktb + tb + kds[i] + lsrc, (char*)K_lds[0] + kds[i]);
      gload16(vnb + tb + kds[i] + lsrc, (char*)V_lds[0] + kds[i]);
    }
  }
  __syncthreads();

  int cur = 0;
  for (int t = 0; t < 64; ++t) {
    if (t < 63) {
      size_t tb = (size_t)(slice*64 + t + 1) * 16384;
      #pragma unroll
      for (int i = 0; i < 4; ++i) {
        gload16(ktb + tb + kds[i] + lsrc, (char*)K_lds[cur^1] + kds[i]);
        gload16(vnb + tb + kds[i] + lsrc, (char*)V_lds[cur^1] + kds[i]);
      }
    }

    const char* Kb = (const char*)K_lds[cur] + lsrc;
    const char* Vb = (const char*)V_lds[cur] + lsrc;

    // S^T = K @ Q^T via mfma32 (A=K rows=p, B=Q cols=q): lane ln holds
    // S[p=(r&3)+8*(r>>2)+4*h2][q=ln] in regs r=0..15. Two interleaved chains.
    f32x16 Sa = {}, Sb = {};
    #pragma unroll
    for (int kc = 0; kc < 8; ++kc) {
      bf16x8 k0 = ld_bf8(Kb + (2*kc)*1024);
      bf16x8 k1 = ld_bf8(Kb + (2*kc+1)*1024);
      Sa = mfma32b(k0, qf[2*kc], Sa);
      Sb = mfma32b(k1, qf[2*kc+1], Sb);
    }
    float S[16];
    #pragma unroll
    for (int r = 0; r < 16; ++r) S[r] = Sa[r] + Sb[r];

    // SPECULATIVE: P = exp2(S - m_old) immediately (no dep on max-reduce)
    float Pr[16];
    #pragma unroll
    for (int r = 0; r < 16; ++r) Pr[r] = fexp2(S[r] - m);

    // lane-local max (q = ln): pairwise tree + cross-half swap
    float x0 = fmaxf(S[0], S[1]),  x1 = fmaxf(S[2], S[3]);
    float x2 = fmaxf(S[4], S[5]),  x3 = fmaxf(S[6], S[7]);
    float x4 = fmaxf(S[8], S[9]),  x5 = fmaxf(S[10], S[11]);
    float x6 = fmaxf(S[12], S[13]), x7 = fmaxf(S[14], S[15]);
    float px = fmaxf(fmaxf(fmaxf(x0, x1), fmaxf(x2, x3)),
                     fmaxf(fmaxf(x4, x5), fmaxf(x6, x7)));
    px = fmaxf(px, __shfl_xor(px, 32));

    // defer-max fixup: rare path; Pr fix is the lane's own sc (its q = ln)
    if (__any((int)(px > m + 5.5f))) {
      float mn = fmaxf(m, px);
      float sc = fexp2(m - mn);
      m = mn;
      accs *= sc;
      #pragma unroll
      for (int r = 0; r < 16; ++r) Pr[r] *= sc;
      if (lane < 32) Sc[w][lane] = sc;   // broadcast per-q scale for acc32
      f32x4 s4[4];
      #pragma unroll
      for (int blk = 0; blk < 4; ++blk)
        s4[blk] = *(const f32x4*)&Sc[w][8*blk + 4*h2];
      #pragma unroll
      for (int fb = 0; fb < 8; ++fb)
        #pragma unroll
        for (int r = 0; r < 16; ++r)
          acc32[fb][r] *= s4[r>>2][r&3];
    }

    // rowsum + pack into PV A-fragments
    float sum = (((Pr[0]+Pr[1])+(Pr[2]+Pr[3])) + ((Pr[4]+Pr[5])+(Pr[6]+Pr[7])))
              + (((Pr[8]+Pr[9])+(Pr[10]+Pr[11])) + ((Pr[12]+Pr[13])+(Pr[14]+Pr[15])));
    sum += __shfl_xor(sum, 32);
    accs += sum;
    u32x4 w0, w1;
    #pragma unroll
    for (int j = 0; j < 4; ++j) {
      w0[j] = pk_f16(Pr[2*j],   Pr[2*j+1]);
      w1[j] = pk_f16(Pr[8+2*j], Pr[8+2*j+1]);
    }
    f16x8 pa0 = __builtin_bit_cast(f16x8, w0);
    f16x8 pa1 = __builtin_bit_cast(f16x8, w1);

    // PV via mfma32h: A = packed P (row=q=ln, k per poolVF sigma), B = V frags
    #pragma unroll
    for (int fb = 0; fb < 8; ++fb) {
      f16x8 v0 = ld_f8(Vb + fb*1024);
      acc32[fb] = mfma32h(pa0, v0, acc32[fb]);
    }
    #pragma unroll
    for (int fb = 0; fb < 8; ++fb) {
      f16x8 v1 = ld_f8(Vb + (8 + fb)*1024);
      acc32[fb] = mfma32h(pa1, v1, acc32[fb]);
    }

    __syncthreads();   // tile t+1 staged by all waves; buf cur free for t+2
    cur ^= 1;
  }

  // ---- epilogue: per-slice normalized output (f16) + (m, rowsum) ----
  if (lane < 32) As[w][lane] = accs;
  float inv[16];
  #pragma unroll
  for (int blk = 0; blk < 4; ++blk) {
    f32x4 a4 = *(const f32x4*)&As[w][8*blk + 4*h2];
    inv[blk*4+0] = 1.0f / a4[0]; inv[blk*4+1] = 1.0f / a4[1];
    inv[blk*4+2] = 1.0f / a4[2]; inv[blk*4+3] = 1.0f / a4[3];
  }
  size_t sbase = (size_t)slice * 16384 + qa0;
  #pragma unroll
  for (int fb = 0; fb < 8; ++fb) {
    #pragma unroll
    for (int r = 0; r < 16; ++r) {
      int q = (r & 3) + 8*(r >> 2) + 4*h2;
      accP[(sbase + q) * 256 + fb*32 + ln] = (_Float16)(acc32[fb][r] * inv[r]);
    }
  }
  if (lane < 32) {            // per-q scalars live at lane q
    pm[sbase + lane] = m;     // log2-domain running max
    ps[sbase + lane] = accs;  // rowsum
  }
}

// ---------------- combine the 4 pool-slice partials (pre-normalized, log2 m) --
__global__ __launch_bounds__(256) void k_comb(const _Float16* __restrict__ accP,
                                              const float* __restrict__ pm,
                                              const float* __restrict__ ps,
                                              unsigned short* __restrict__ agg){
  int q = blockIdx.x * 16 + (threadIdx.x >> 4);
  int f0 = (threadIdx.x & 15) * 16;
  float m0 = pm[q], m1 = pm[16384 + q], m2 = pm[2*16384 + q], m3 = pm[3*16384 + q];
  float M = fmaxf(fmaxf(m0, m1), fmaxf(m2, m3));
  float w0 = fexp2(m0 - M) * ps[q];
  float w1 = fexp2(m1 - M) * ps[16384 + q];
  float w2 = fexp2(m2 - M) * ps[2*16384 + q];
  float w3 = fexp2(m3 - M) * ps[3*16384 + q];
  float inv = 1.0f / (w0 + w1 + w2 + w3);
  w0 *= inv; w1 *= inv; w2 *= inv; w3 *= inv;
  const _Float16* a0 = accP + (size_t)q * 256 + f0;
  #pragma unroll
  for (int j = 0; j < 16; j += 8) {
    f16x8 v0 = *(const f16x8*)(a0 + j);
    f16x8 v1 = *(const f16x8*)(a0 + j + (size_t)16384*256);
    f16x8 v2 = *(const f16x8*)(a0 + j + (size_t)2*16384*256);
    f16x8 v3 = *(const f16x8*)(a0 + j + (size_t)3*16384*256);
    u16x8 o;
    #pragma unroll
    for (int k = 0; k < 8; ++k) {
      float s = w0*(float)v0[k] + w1*(float)v1[k] + w2*(float)v2[k] + w3*(float)v3[k];
      o[k] = f2bf(s);
    }
    *(u16x8*)(agg + (size_t)q * 256 + f0 + j) = o;
  }
}

// ---------------- output GEMM + gated residual ----------------
__global__ __launch_bounds__(256) void k_out(const float* __restrict__ x,
                                             const unsigned short* __restrict__ wo,
                                             const unsigned short* __restrict__ agg,
                                             const float* __restrict__ gammap,
                                             float* __restrict__ out){
  int w = threadIdx.x >> 6, lane = threadIdx.x & 63;
  int lq = lane & 15, hq = lane >> 4;
  int b = blockIdx.x;
  int lg = b & 63, cg = (b >> 6) & 7, n = b >> 9;
  const char* wb = (const char*)wo;
  const char* ab = (const char*)agg;
  f32x4 acc[4];
  #pragma unroll
  for (int i = 0; i < 4; ++i) acc[i] = {};
  int crow = cg*64 + w*16 + lq;
  #pragma unroll
  for (int kk = 0; kk < 8; ++kk) {
    bf16x8 a = ld_bf8(wb + (size_t)crow * 512 + kk*64 + hq*16);
    #pragma unroll
    for (int li = 0; li < 4; ++li) {
      bf16x8 bb = ld_bf8(ab + (size_t)(n*HWD + lg*64 + li*16 + lq) * 512 + kk*64 + hq*16);
      acc[li] = mfma16(a, bb, acc[li]);
    }
  }
  float g = gammap[0];
  #pragma unroll
  for (int li = 0; li < 4; ++li) {
    #pragma unroll
    for (int r = 0; r < 4; ++r) {
      int c = cg*64 + w*16 + hq*4 + r;
      int l = lg*64 + li*16 + lq;
      size_t idx = ((size_t)(n*CHN + c)) * HWD + l;
      out[idx] = x[idx] + g * acc[li][r];
    }
  }
}

extern "C" void kernel_launch(void* const* d_in, const int* in_sizes, int n_in,
                              void* d_out, int out_size, void* d_ws, size_t ws_size,
                              hipStream_t stream) {
  const float* x     = (const float*)d_in[0];
  const float* wt    = (const float*)d_in[1];
  const float* wo    = (const float*)d_in[2];
  const float* pool  = (const float*)d_in[3];
  const float* gamma = (const float*)d_in[4];
  char* ws = (char*)d_ws;
  unsigned short* wt_b  = (unsigned short*)(ws + 0);         // 256 KB
  unsigned short* wo_b  = (unsigned short*)(ws + 262144);    // 256 KB
  _Float16*       poolVF= (_Float16*)(ws + 524288);          // 4 MB (fragment-major f16)
  unsigned short* poolKF= (unsigned short*)(ws + 4718592);   // 4 MB (fragment-major bf16)
  unsigned short* Qb    = (unsigned short*)(ws + 8912896);   // 8 MB
  unsigned short* aggb  = (unsigned short*)(ws + 17301504);  // 8 MB
  unsigned short* xT    = (unsigned short*)(ws + 25690112);  // 16 MB (dead after k_theta)
  _Float16*       accP  = (_Float16*)(ws + 25690112);        // 32 MB (overlaps dead xT)
  float*          pm    = (float*)(ws + 59244544);           // 256 KB
  float*          ps    = (float*)(ws + 59506688);           // 256 KB
  float* out = (float*)d_out;

  k_cvtw<<<dim3(256), dim3(256), 0, stream>>>(wt, wo, wt_b, wo_b);
  k_poolF<<<dim3(2048), dim3(256), 0, stream>>>(pool, poolKF, poolVF);
  k_xT<<<dim3(8192), dim3(256), 0, stream>>>(x, xT);
  k_theta<<<dim3(256), dim3(256), 0, stream>>>(xT, wt_b, Qb);
  k_attn<<<dim3(512), dim3(256), 0, stream>>>(Qb, poolKF, poolVF, accP, pm, ps);
  k_comb<<<dim3(1024), dim3(256), 0, stream>>>(accP, pm, ps, aggb);
  k_out<<<dim3(2048), dim3(256), 0, stream>>>(x, wo_b, aggb, gamma, out);
}